// Round 1
// baseline (613.364 us; speedup 1.0000x reference)
//
#include <hip/hip_runtime.h>
#include <hip/hip_bf16.h>

typedef __attribute__((ext_vector_type(8))) short short8;
typedef __attribute__((ext_vector_type(4))) float f32x4;
typedef __attribute__((ext_vector_type(4))) unsigned short us4;

#define MFMA16(a,b,c) __builtin_amdgcn_mfma_f32_16x16x32_bf16((a),(b),(c),0,0,0)

__device__ __forceinline__ unsigned short f2bf(float x){
  union{float f; unsigned u;} v; v.f=x;
  unsigned r = v.u + 0x7fffu + ((v.u>>16)&1u);
  return (unsigned short)(r>>16);
}
__device__ __forceinline__ float bf2f(unsigned short u){
  union{unsigned u; float f;} v; v.u = ((unsigned)u)<<16; return v.f;
}

// ---------------- weights f32 -> bf16 (wq|wk|wv|wo contiguous) ----------------
__global__ __launch_bounds__(256) void prep_kernel(
    const float* __restrict__ wq, const float* __restrict__ wk,
    const float* __restrict__ wv, const float* __restrict__ wo,
    unsigned short* __restrict__ dst){
  int idx = (blockIdx.x*256 + threadIdx.x)*4;
  const float* srcs[4] = {wq, wk, wv, wo};
  int m = idx >> 16;
  float4 v = *(const float4*)(srcs[m] + (idx & 65535));
  us4 o; o[0]=f2bf(v.x); o[1]=f2bf(v.y); o[2]=f2bf(v.z); o[3]=f2bf(v.w);
  *(us4*)(dst + idx) = o;
}

// ---------------- GroupNorm: x (B,C,HW) f32 -> xn bf16 in two layouts ----------
// xn_cm: (B,C,HW) channel-major (for residual); xn_pm: (B,HW,C) pixel-major (GEMM)
__global__ __launch_bounds__(256) void gn_kernel(
    const float* __restrict__ x, const float* __restrict__ gamma,
    const float* __restrict__ beta,
    unsigned short* __restrict__ xn_cm, unsigned short* __restrict__ xn_pm){
  int b = blockIdx.x >> 5, g = blockIdx.x & 31;
  int t = threadIdx.x;
  const float* xb = x + (size_t)(b*256 + g*8)*1024;
  float4 v[8]; float s=0.f, ss=0.f;
  #pragma unroll
  for(int j=0;j<8;++j){               // chunk j = channel j, pixels 4t..4t+3
    v[j] = ((const float4*)xb)[j*256 + t];
    s  += v[j].x+v[j].y+v[j].z+v[j].w;
    ss += v[j].x*v[j].x+v[j].y*v[j].y+v[j].z*v[j].z+v[j].w*v[j].w;
  }
  #pragma unroll
  for(int m=1;m<64;m<<=1){ s += __shfl_xor(s,m); ss += __shfl_xor(ss,m); }
  __shared__ float red[8];
  if((t&63)==0){ red[t>>6]=s; red[4+(t>>6)]=ss; }
  __syncthreads();
  s  = red[0]+red[1]+red[2]+red[3];
  ss = red[4]+red[5]+red[6]+red[7];
  float mean = s*(1.f/8192.f);
  float rstd = rsqrtf(ss*(1.f/8192.f) - mean*mean + 1e-5f);
  float fn[8][4];
  #pragma unroll
  for(int j=0;j<8;++j){
    float ga = gamma[g*8+j]*rstd;
    float be = beta[g*8+j] - mean*ga;
    fn[j][0]=v[j].x*ga+be; fn[j][1]=v[j].y*ga+be;
    fn[j][2]=v[j].z*ga+be; fn[j][3]=v[j].w*ga+be;
    us4 o; o[0]=f2bf(fn[j][0]); o[1]=f2bf(fn[j][1]);
          o[2]=f2bf(fn[j][2]); o[3]=f2bf(fn[j][3]);
    *(us4*)(xn_cm + (size_t)(b*256 + g*8 + j)*1024 + 4*t) = o;
  }
  #pragma unroll
  for(int pp=0;pp<4;++pp){
    short8 w8;
    #pragma unroll
    for(int j=0;j<8;++j) w8[j] = (short)f2bf(fn[j][pp]);
    *(short8*)(xn_pm + (size_t)(b*1024 + 4*t + pp)*256 + g*8) = w8;
  }
}

// ---------------- QKV projection GEMMs ----------------
// z=0(Q),1(K): D[o][p] = W * XnT   -> store pixel-major q/k (4 consec o per lane)
// z=2(V):      D[p][o] = XnT * W^T -> store channel-major vT (4 consec p per lane)
__global__ __launch_bounds__(256) void qkv_kernel(
    const unsigned short* __restrict__ xn_pm, const unsigned short* __restrict__ wbf,
    const float* __restrict__ bq, const float* __restrict__ bk,
    const float* __restrict__ bv,
    unsigned short* __restrict__ qb, unsigned short* __restrict__ kb,
    unsigned short* __restrict__ vTb){
  int b = blockIdx.y, z = blockIdx.z;
  int otile = blockIdx.x & 3, ptile = blockIdx.x >> 2;
  int t = threadIdx.x, w = t>>6, lane = t&63, lo = lane&15, hi = lane>>4;
  const unsigned short* W = wbf + (size_t)z*65536;
  const float* bias = (z==0)? bq : ((z==1)? bk : bv);
  const unsigned short* xb = xn_pm + (size_t)b*1024*256;
  int p0 = ptile*256 + w*64;
  f32x4 acc[4][4] = {};
  if(z < 2){
    #pragma unroll
    for(int kk=0;kk<8;++kk){
      short8 af[4], bfr[4];
      #pragma unroll
      for(int r=0;r<4;++r)
        af[r] = *(const short8*)(W + (size_t)(otile*64 + r*16 + lo)*256 + kk*32 + hi*8);
      #pragma unroll
      for(int c=0;c<4;++c)
        bfr[c] = *(const short8*)(xb + (size_t)(p0 + c*16 + lo)*256 + kk*32 + hi*8);
      #pragma unroll
      for(int r=0;r<4;++r)
        #pragma unroll
        for(int c=0;c<4;++c) acc[r][c] = MFMA16(af[r], bfr[c], acc[r][c]);
    }
    unsigned short* dst = (z==0)? qb : kb;
    float scale = (z==0)? 0.125f : 1.0f;   // attention scale folded into Q (exact pow2)
    #pragma unroll
    for(int r=0;r<4;++r){
      int ob = otile*64 + r*16 + hi*4;
      float4 bi = *(const float4*)(bias + ob);
      float bia[4] = {bi.x, bi.y, bi.z, bi.w};
      #pragma unroll
      for(int c=0;c<4;++c){
        int p = p0 + c*16 + lo;
        us4 stv;
        #pragma unroll
        for(int rg=0; rg<4; ++rg) stv[rg] = f2bf((acc[r][c][rg] + bia[rg])*scale);
        *(us4*)(dst + (size_t)(b*1024 + p)*256 + ob) = stv;
      }
    }
  } else {
    #pragma unroll
    for(int kk=0;kk<8;++kk){
      short8 af[4], bfr[4];
      #pragma unroll
      for(int r=0;r<4;++r)
        af[r] = *(const short8*)(xb + (size_t)(p0 + r*16 + lo)*256 + kk*32 + hi*8);
      #pragma unroll
      for(int c=0;c<4;++c)
        bfr[c] = *(const short8*)(W + (size_t)(otile*64 + c*16 + lo)*256 + kk*32 + hi*8);
      #pragma unroll
      for(int r=0;r<4;++r)
        #pragma unroll
        for(int c=0;c<4;++c) acc[r][c] = MFMA16(af[r], bfr[c], acc[r][c]);
    }
    #pragma unroll
    for(int c=0;c<4;++c){
      int o = otile*64 + c*16 + lo;
      float bia = bias[o];
      #pragma unroll
      for(int r=0;r<4;++r){
        int pb = p0 + r*16 + hi*4;
        us4 stv;
        #pragma unroll
        for(int rg=0; rg<4; ++rg) stv[rg] = f2bf(acc[r][c][rg] + bia);
        *(us4*)(vTb + (size_t)b*262144 + (size_t)o*1024 + pb) = stv;
      }
    }
  }
}

// ---------------- Fused flash attention + out-proj + residual ----------------
// 4 waves x 16 q-rows (BM=64), KV tile = 32, online softmax.
// LDS rows padded (264 / 40 ushorts) to avoid stride-512B bank conflicts.
__global__ __launch_bounds__(256) void attn_kernel(
    const unsigned short* __restrict__ qb, const unsigned short* __restrict__ kb,
    const unsigned short* __restrict__ vT, const unsigned short* __restrict__ wo_bf,
    const float* __restrict__ bo, const unsigned short* __restrict__ xn_cm,
    float* __restrict__ out){
  int qt = blockIdx.x, b = blockIdx.y;
  int t = threadIdx.x, w = t>>6, lane = t&63, lo = lane&15, hi = lane>>4;
  __shared__ unsigned short smem_u[21248];          // 42.5 KB
  unsigned short* k_lds = smem_u;                   // [32][264]
  unsigned short* v_lds = smem_u + 8448;            // [256][40]
  unsigned short* p_lds = smem_u + 18688 + w*640;   // per-wave [16][40]
  unsigned short* o_lds = smem_u + w*4224;          // per-wave [16][264] (reuses k/v)

  // Q fragments held in registers the whole time (pre-scaled by 0.125)
  short8 aq[8];
  const unsigned short* qrow = qb + (size_t)(b*1024 + qt*64 + w*16 + lo)*256;
  #pragma unroll
  for(int kk=0;kk<8;++kk) aq[kk] = *(const short8*)(qrow + kk*32 + hi*8);

  f32x4 oc[16] = {};
  float mr[4] = {-1e30f,-1e30f,-1e30f,-1e30f};
  float lr[4] = {0.f,0.f,0.f,0.f};

  const unsigned short* kbase = kb + (size_t)b*1024*256;
  const unsigned short* vbase = vT + (size_t)b*256*1024;

  for(int kv0=0; kv0<1024; kv0+=32){
    __syncthreads();
    // stage K tile (32 rows x 512B, contiguous in global)
    {
      const short8* src = (const short8*)(kbase + (size_t)kv0*256);
      #pragma unroll
      for(int i=0;i<4;++i){
        int u = i*256 + t;
        *(short8*)(k_lds + (u>>5)*264 + (u&31)*8) = src[u];
      }
      // stage V^T tile (256 rows x 64B, row stride 2KB in global)
      #pragma unroll
      for(int i=0;i<4;++i){
        int u = i*256 + t;
        int c = u>>2, part = u&3;
        *(short8*)(v_lds + c*40 + part*8) =
            *(const short8*)(vbase + (size_t)c*1024 + kv0 + part*8);
      }
    }
    __syncthreads();
    // S = Q K^T (already scaled via Q)
    f32x4 sc[2] = {};
    #pragma unroll
    for(int kk=0;kk<8;++kk){
      short8 b0 = *(const short8*)(k_lds + lo*264      + kk*32 + hi*8);
      short8 b1 = *(const short8*)(k_lds + (16+lo)*264 + kk*32 + hi*8);
      sc[0] = MFMA16(aq[kk], b0, sc[0]);
      sc[1] = MFMA16(aq[kk], b1, sc[1]);
    }
    // online softmax, row r lives in (hi group, reg r); cols across 16 lanes x 2 frags
    float pr[2][4];
    #pragma unroll
    for(int r=0;r<4;++r){
      float tm = fmaxf(sc[0][r], sc[1][r]);
      tm = fmaxf(tm, __shfl_xor(tm,1)); tm = fmaxf(tm, __shfl_xor(tm,2));
      tm = fmaxf(tm, __shfl_xor(tm,4)); tm = fmaxf(tm, __shfl_xor(tm,8));
      float mnew  = fmaxf(mr[r], tm);
      float alpha = __expf(mr[r]-mnew);
      mr[r] = mnew;
      float p0v = __expf(sc[0][r]-mnew);
      float p1v = __expf(sc[1][r]-mnew);
      pr[0][r]=p0v; pr[1][r]=p1v;
      float rs = p0v + p1v;
      rs += __shfl_xor(rs,1); rs += __shfl_xor(rs,2);
      rs += __shfl_xor(rs,4); rs += __shfl_xor(rs,8);
      lr[r] = lr[r]*alpha + rs;
      #pragma unroll
      for(int f=0; f<16; ++f) oc[f][r] *= alpha;
    }
    // P: D-layout -> A-layout via per-wave padded LDS scratch
    #pragma unroll
    for(int cf=0;cf<2;++cf)
      #pragma unroll
      for(int r=0;r<4;++r)
        p_lds[(hi*4+r)*40 + cf*16 + lo] = f2bf(pr[cf][r]);
    short8 pa = *(const short8*)(p_lds + lo*40 + hi*8);
    // O += P V
    #pragma unroll
    for(int f=0; f<16; ++f){
      short8 bv = *(const short8*)(v_lds + (f*16+lo)*40 + hi*8);
      oc[f] = MFMA16(pa, bv, oc[f]);
    }
  }

  // normalize, transpose O through LDS, then fused out-projection + residual
  float inv[4];
  #pragma unroll
  for(int r=0;r<4;++r) inv[r] = 1.f/lr[r];
  __syncthreads();
  #pragma unroll
  for(int f=0;f<16;++f)
    #pragma unroll
    for(int r=0;r<4;++r)
      o_lds[(hi*4+r)*264 + f*16 + lo] = f2bf(oc[f][r]*inv[r]);

  f32x4 a2[16] = {};
  #pragma unroll
  for(int kk=0;kk<8;++kk){
    short8 pa2 = *(const short8*)(o_lds + lo*264 + kk*32 + hi*8);
    #pragma unroll
    for(int cf=0;cf<16;++cf){
      short8 wb = *(const short8*)(wo_bf + (size_t)(cf*16+lo)*256 + kk*32 + hi*8);
      a2[cf] = MFMA16(pa2, wb, a2[cf]);
    }
  }
  int p0 = qt*64 + w*16 + hi*4;
  #pragma unroll
  for(int cf=0;cf<16;++cf){
    int o = cf*16 + lo;
    float bia = bo[o];
    us4 xr = *(const us4*)(xn_cm + (size_t)(b*256+o)*1024 + p0);
    float4 st;
    st.x = a2[cf][0] + bia + bf2f(xr[0]);
    st.y = a2[cf][1] + bia + bf2f(xr[1]);
    st.z = a2[cf][2] + bia + bf2f(xr[2]);
    st.w = a2[cf][3] + bia + bf2f(xr[3]);
    *(float4*)(out + (size_t)(b*256+o)*1024 + p0) = st;
  }
}

extern "C" void kernel_launch(void* const* d_in, const int* in_sizes, int n_in,
                              void* d_out, int out_size, void* d_ws, size_t ws_size,
                              hipStream_t stream){
  (void)in_sizes; (void)n_in; (void)out_size; (void)ws_size;
  const float* x     = (const float*)d_in[0];
  const float* wq    = (const float*)d_in[1];
  const float* bq    = (const float*)d_in[2];
  const float* wk    = (const float*)d_in[3];
  const float* bk    = (const float*)d_in[4];
  const float* wv    = (const float*)d_in[5];
  const float* bv    = (const float*)d_in[6];
  const float* wo    = (const float*)d_in[7];
  const float* bo    = (const float*)d_in[8];
  const float* gamma = (const float*)d_in[9];
  const float* beta  = (const float*)d_in[10];
  float* out = (float*)d_out;
  char* ws = (char*)d_ws;
  unsigned short* xn_cm = (unsigned short*)(ws);              // 33,554,432 B
  unsigned short* xn_pm = (unsigned short*)(ws + 33554432);   // 33,554,432 B
  unsigned short* qb    = (unsigned short*)(ws + 67108864);   // 33,554,432 B
  unsigned short* kb    = (unsigned short*)(ws + 100663296);  // 33,554,432 B
  unsigned short* vT    = (unsigned short*)(ws + 134217728);  // 33,554,432 B
  unsigned short* wbf   = (unsigned short*)(ws + 167772160);  // 524,288 B

  hipLaunchKernelGGL(prep_kernel, dim3(256), dim3(256), 0, stream, wq, wk, wv, wo, wbf);
  hipLaunchKernelGGL(gn_kernel,   dim3(2048), dim3(256), 0, stream, x, gamma, beta, xn_cm, xn_pm);
  hipLaunchKernelGGL(qkv_kernel,  dim3(16,64,3), dim3(256), 0, stream,
                     xn_pm, wbf, bq, bk, bv, qb, kb, vT);
  hipLaunchKernelGGL(attn_kernel, dim3(16,64), dim3(256), 0, stream,
                     qb, kb, vT, wbf + 3*65536, bo, xn_cm, out);
}

// Round 2
// 543.783 us; speedup vs baseline: 1.1280x; 1.1280x over previous
//
#include <hip/hip_runtime.h>
#include <hip/hip_bf16.h>

typedef __attribute__((ext_vector_type(8))) short short8;
typedef __attribute__((ext_vector_type(4))) float f32x4;
typedef __attribute__((ext_vector_type(4))) unsigned short us4;

#define MFMA16(a,b,c) __builtin_amdgcn_mfma_f32_16x16x32_bf16((a),(b),(c),0,0,0)
#define GLOAD16(g,l) __builtin_amdgcn_global_load_lds( \
    (const __attribute__((address_space(1))) void*)(g), \
    (__attribute__((address_space(3))) void*)(l), 16, 0, 0)

__device__ __forceinline__ unsigned short f2bf(float x){
  union{float f; unsigned u;} v; v.f=x;
  unsigned r = v.u + 0x7fffu + ((v.u>>16)&1u);
  return (unsigned short)(r>>16);
}
__device__ __forceinline__ float bf2f(unsigned short u){
  union{unsigned u; float f;} v; v.u = ((unsigned)u)<<16; return v.f;
}

// ---------------- weights f32 -> bf16 (wq|wk|wv|wo contiguous) ----------------
__global__ __launch_bounds__(256) void prep_kernel(
    const float* __restrict__ wq, const float* __restrict__ wk,
    const float* __restrict__ wv, const float* __restrict__ wo,
    unsigned short* __restrict__ dst){
  int idx = (blockIdx.x*256 + threadIdx.x)*4;
  const float* srcs[4] = {wq, wk, wv, wo};
  int m = idx >> 16;
  float4 v = *(const float4*)(srcs[m] + (idx & 65535));
  us4 o; o[0]=f2bf(v.x); o[1]=f2bf(v.y); o[2]=f2bf(v.z); o[3]=f2bf(v.w);
  *(us4*)(dst + idx) = o;
}

// ---------------- GroupNorm: x (B,C,HW) f32 -> xn bf16 in two layouts ----------
__global__ __launch_bounds__(256) void gn_kernel(
    const float* __restrict__ x, const float* __restrict__ gamma,
    const float* __restrict__ beta,
    unsigned short* __restrict__ xn_cm, unsigned short* __restrict__ xn_pm){
  int b = blockIdx.x >> 5, g = blockIdx.x & 31;
  int t = threadIdx.x;
  const float* xb = x + (size_t)(b*256 + g*8)*1024;
  float4 v[8]; float s=0.f, ss=0.f;
  #pragma unroll
  for(int j=0;j<8;++j){
    v[j] = ((const float4*)xb)[j*256 + t];
    s  += v[j].x+v[j].y+v[j].z+v[j].w;
    ss += v[j].x*v[j].x+v[j].y*v[j].y+v[j].z*v[j].z+v[j].w*v[j].w;
  }
  #pragma unroll
  for(int m=1;m<64;m<<=1){ s += __shfl_xor(s,m); ss += __shfl_xor(ss,m); }
  __shared__ float red[8];
  if((t&63)==0){ red[t>>6]=s; red[4+(t>>6)]=ss; }
  __syncthreads();
  s  = red[0]+red[1]+red[2]+red[3];
  ss = red[4]+red[5]+red[6]+red[7];
  float mean = s*(1.f/8192.f);
  float rstd = rsqrtf(ss*(1.f/8192.f) - mean*mean + 1e-5f);
  float fn[8][4];
  #pragma unroll
  for(int j=0;j<8;++j){
    float ga = gamma[g*8+j]*rstd;
    float be = beta[g*8+j] - mean*ga;
    fn[j][0]=v[j].x*ga+be; fn[j][1]=v[j].y*ga+be;
    fn[j][2]=v[j].z*ga+be; fn[j][3]=v[j].w*ga+be;
    us4 o; o[0]=f2bf(fn[j][0]); o[1]=f2bf(fn[j][1]);
          o[2]=f2bf(fn[j][2]); o[3]=f2bf(fn[j][3]);
    *(us4*)(xn_cm + (size_t)(b*256 + g*8 + j)*1024 + 4*t) = o;
  }
  #pragma unroll
  for(int pp=0;pp<4;++pp){
    short8 w8;
    #pragma unroll
    for(int j=0;j<8;++j) w8[j] = (short)f2bf(fn[j][pp]);
    *(short8*)(xn_pm + (size_t)(b*1024 + 4*t + pp)*256 + g*8) = w8;
  }
}

// ---------------- QKV projection GEMMs ----------------
__global__ __launch_bounds__(256) void qkv_kernel(
    const unsigned short* __restrict__ xn_pm, const unsigned short* __restrict__ wbf,
    const float* __restrict__ bq, const float* __restrict__ bk,
    const float* __restrict__ bv,
    unsigned short* __restrict__ qb, unsigned short* __restrict__ kb,
    unsigned short* __restrict__ vTb){
  int b = blockIdx.y, z = blockIdx.z;
  int otile = blockIdx.x & 3, ptile = blockIdx.x >> 2;
  int t = threadIdx.x, w = t>>6, lane = t&63, lo = lane&15, hi = lane>>4;
  const unsigned short* W = wbf + (size_t)z*65536;
  const float* bias = (z==0)? bq : ((z==1)? bk : bv);
  const unsigned short* xb = xn_pm + (size_t)b*1024*256;
  int p0 = ptile*256 + w*64;
  f32x4 acc[4][4] = {};
  if(z < 2){
    #pragma unroll
    for(int kk=0;kk<8;++kk){
      short8 af[4], bfr[4];
      #pragma unroll
      for(int r=0;r<4;++r)
        af[r] = *(const short8*)(W + (size_t)(otile*64 + r*16 + lo)*256 + kk*32 + hi*8);
      #pragma unroll
      for(int c=0;c<4;++c)
        bfr[c] = *(const short8*)(xb + (size_t)(p0 + c*16 + lo)*256 + kk*32 + hi*8);
      #pragma unroll
      for(int r=0;r<4;++r)
        #pragma unroll
        for(int c=0;c<4;++c) acc[r][c] = MFMA16(af[r], bfr[c], acc[r][c]);
    }
    unsigned short* dst = (z==0)? qb : kb;
    float scale = (z==0)? 0.125f : 1.0f;
    #pragma unroll
    for(int r=0;r<4;++r){
      int ob = otile*64 + r*16 + hi*4;
      float4 bi = *(const float4*)(bias + ob);
      float bia[4] = {bi.x, bi.y, bi.z, bi.w};
      #pragma unroll
      for(int c=0;c<4;++c){
        int p = p0 + c*16 + lo;
        us4 stv;
        #pragma unroll
        for(int rg=0; rg<4; ++rg) stv[rg] = f2bf((acc[r][c][rg] + bia[rg])*scale);
        *(us4*)(dst + (size_t)(b*1024 + p)*256 + ob) = stv;
      }
    }
  } else {
    #pragma unroll
    for(int kk=0;kk<8;++kk){
      short8 af[4], bfr[4];
      #pragma unroll
      for(int r=0;r<4;++r)
        af[r] = *(const short8*)(xb + (size_t)(p0 + r*16 + lo)*256 + kk*32 + hi*8);
      #pragma unroll
      for(int c=0;c<4;++c)
        bfr[c] = *(const short8*)(W + (size_t)(otile*64 + c*16 + lo)*256 + kk*32 + hi*8);
      #pragma unroll
      for(int r=0;r<4;++r)
        #pragma unroll
        for(int c=0;c<4;++c) acc[r][c] = MFMA16(af[r], bfr[c], acc[r][c]);
    }
    #pragma unroll
    for(int c=0;c<4;++c){
      int o = otile*64 + c*16 + lo;
      float bia = bias[o];
      #pragma unroll
      for(int r=0;r<4;++r){
        int pb = p0 + r*16 + hi*4;
        us4 stv;
        #pragma unroll
        for(int rg=0; rg<4; ++rg) stv[rg] = f2bf(acc[r][c][rg] + bia);
        *(us4*)(vTb + (size_t)b*262144 + (size_t)o*1024 + pb) = stv;
      }
    }
  }
}

// ---------------- Fused flash attention + out-proj + residual ----------------
// BM=128, 8 waves x 16 q-rows, KVBLK=32. Double-buffered K/V staged via
// global_load_lds (linear LDS, XOR-swizzle via pre-swizzled global source).
// One barrier per KV tile; defer-max softmax (THR=8); per-lane partial row-sums.
__global__ __launch_bounds__(512, 4) void attn_kernel(
    const unsigned short* __restrict__ qb, const unsigned short* __restrict__ kb,
    const unsigned short* __restrict__ vT, const unsigned short* __restrict__ wo_bf,
    const float* __restrict__ bo, const unsigned short* __restrict__ xn_cm,
    float* __restrict__ out){
  int flat = blockIdx.x;
  int xcd = flat & 7, rest = flat >> 3;
  int b = xcd*8 + (rest>>3), qt = rest & 7;   // XCD-chunked: each XCD owns 8 batches
  int t = threadIdx.x, w = t>>6, lane = t&63, lo = lane&15, hi = lane>>4;

  __shared__ unsigned short smem_u[37888];           // 75,776 B
  unsigned short* kb0 = smem_u;                      // [32][256] linear, swizzled
  unsigned short* kb1 = smem_u + 8192;
  unsigned short* vb0 = smem_u + 16384;              // [256][32] linear, swizzled
  unsigned short* vb1 = smem_u + 24576;
  unsigned short* p_lds = smem_u + 32768 + w*640;    // per-wave [16][40]

  const unsigned short* kbase = kb + (size_t)b*262144;
  const unsigned short* vbase = vT + (size_t)b*262144;

  // Per-lane pre-swizzled staging source offsets (us units).
  // K chunk u: row=u>>5, c=u&31; store[u] = Kglobal[row][c ^ (row&7)]
  int ku0 = w*128 + lane, ku1 = w*128 + 64 + lane;
  int kr0 = ku0>>5, kr1 = ku1>>5;
  int ksrc0 = kr0*256 + ((ku0&31)^(kr0&7))*8;
  int ksrc1 = kr1*256 + ((ku1&31)^(kr1&7))*8;
  // V chunk u: ch=u>>2, c=u&3; store[u] = Vt[ch][kv0 + (c^(ch&3))*8]
  int vc0 = ku0>>2, vc1 = ku1>>2;
  int vsrc0 = vc0*1024 + ((ku0&3)^(vc0&3))*8;
  int vsrc1 = vc1*1024 + ((ku1&3)^(vc1&3))*8;
  int ldsA = (w*128)*8, ldsB = (w*128+64)*8;         // wave-uniform LDS us offsets

  // swizzled read offsets
  int hxl8 = (hi ^ (lo&7))*8;                        // K read: chunk = (kk*4)^ (hi^(lo&7))
  int vroff = lo*32 + (hi^(lo&3))*8;                 // V read base (per f: +f*512)

  // Q fragments in registers (pre-scaled by 0.125)
  short8 aq[8];
  {
    const unsigned short* qrow = qb + (size_t)(b*1024 + qt*128 + w*16 + lo)*256 + hi*8;
    #pragma unroll
    for(int kk=0;kk<8;++kk) aq[kk] = *(const short8*)(qrow + kk*32);
  }
  f32x4 oc[16] = {};
  float mr[4] = {-1e30f,-1e30f,-1e30f,-1e30f};
  float lr[4] = {0.f,0.f,0.f,0.f};

  // prologue: stage tile 0 into buffer 0
  {
    const unsigned short* kg = kbase;
    const unsigned short* vg = vbase;
    GLOAD16(kg + ksrc0, kb0 + 0 + ldsA);  GLOAD16(kg + ksrc1, kb0 + 0 + ldsB);
    GLOAD16(vg + vsrc0, vb0 + 0 + ldsA);  GLOAD16(vg + vsrc1, vb0 + 0 + ldsB);
  }
  __syncthreads();

  for(int tkv=0; tkv<32; ++tkv){
    int cur = tkv & 1;
    unsigned short* kc = cur ? kb1 : kb0;
    unsigned short* vc = cur ? vb1 : vb0;
    if(tkv < 31){                                     // stage next tile (other buffer)
      unsigned short* kn = cur ? kb0 : kb1;
      unsigned short* vn = cur ? vb0 : vb1;
      const unsigned short* kg = kbase + (tkv+1)*32*256;
      const unsigned short* vg = vbase + (tkv+1)*32;
      GLOAD16(kg + ksrc0, kn + ldsA);  GLOAD16(kg + ksrc1, kn + ldsB);
      GLOAD16(vg + vsrc0, vn + ldsA);  GLOAD16(vg + vsrc1, vn + ldsB);
    }
    // S = Q K^T
    f32x4 sc0 = {}, sc1 = {};
    __builtin_amdgcn_s_setprio(1);
    #pragma unroll
    for(int kk=0;kk<8;++kk){
      int coff = (kk*32) ^ hxl8;                      // swizzled 16B chunk offset (us)
      short8 b0 = *(const short8*)(kc + lo*256        + coff);
      short8 b1 = *(const short8*)(kc + lo*256 + 4096 + coff);
      sc0 = MFMA16(aq[kk], b0, sc0);
      sc1 = MFMA16(aq[kk], b1, sc1);
    }
    __builtin_amdgcn_s_setprio(0);
    // online softmax with defer-max
    float tm[4];
    #pragma unroll
    for(int r=0;r<4;++r){
      float m2 = fmaxf(sc0[r], sc1[r]);
      m2 = fmaxf(m2, __shfl_xor(m2,1)); m2 = fmaxf(m2, __shfl_xor(m2,2));
      m2 = fmaxf(m2, __shfl_xor(m2,4)); m2 = fmaxf(m2, __shfl_xor(m2,8));
      tm[r] = m2;
    }
    if(__any((tm[0]>mr[0]+8.f)|(tm[1]>mr[1]+8.f)|(tm[2]>mr[2]+8.f)|(tm[3]>mr[3]+8.f))){
      #pragma unroll
      for(int r=0;r<4;++r){
        float mnew  = fmaxf(mr[r], tm[r]);
        float alpha = __expf(mr[r]-mnew);
        mr[r] = mnew; lr[r] *= alpha;
        #pragma unroll
        for(int f=0; f<16; ++f) oc[f][r] *= alpha;
      }
    }
    #pragma unroll
    for(int r=0;r<4;++r){
      float p0 = __expf(sc0[r]-mr[r]);
      float p1 = __expf(sc1[r]-mr[r]);
      lr[r] += p0 + p1;                               // per-lane partial row-sum
      p_lds[(hi*4+r)*40 + lo]    = f2bf(p0);
      p_lds[(hi*4+r)*40 + 16+lo] = f2bf(p1);
    }
    short8 pa = *(const short8*)(p_lds + lo*40 + hi*8);
    // O += P V
    __builtin_amdgcn_s_setprio(1);
    #pragma unroll
    for(int f=0; f<16; ++f){
      short8 bv = *(const short8*)(vc + f*512 + vroff);
      oc[f] = MFMA16(pa, bv, oc[f]);
    }
    __builtin_amdgcn_s_setprio(0);
    __syncthreads();                                  // drains vmcnt (stage) + lgkm
  }

  // finalize row sums (reduce the per-lane partials across the 16-lane group)
  #pragma unroll
  for(int r=0;r<4;++r){
    lr[r] += __shfl_xor(lr[r],1); lr[r] += __shfl_xor(lr[r],2);
    lr[r] += __shfl_xor(lr[r],4); lr[r] += __shfl_xor(lr[r],8);
  }
  float inv[4];
  #pragma unroll
  for(int r=0;r<4;++r) inv[r] = 1.f/lr[r];

  // O normalize -> per-wave LDS transpose -> fused out-proj + bias + residual
  unsigned short* o_lds = smem_u + w*4224;            // [16][264]
  #pragma unroll
  for(int f=0;f<16;++f)
    #pragma unroll
    for(int r=0;r<4;++r)
      o_lds[(hi*4+r)*264 + f*16 + lo] = f2bf(oc[f][r]*inv[r]);

  f32x4 a2[16] = {};
  #pragma unroll
  for(int kk=0;kk<8;++kk){
    short8 pa2 = *(const short8*)(o_lds + lo*264 + kk*32 + hi*8);
    #pragma unroll
    for(int cf=0;cf<16;++cf){
      short8 wb = *(const short8*)(wo_bf + (size_t)(cf*16+lo)*256 + kk*32 + hi*8);
      a2[cf] = MFMA16(pa2, wb, a2[cf]);
    }
  }
  int p0r = qt*128 + w*16 + hi*4;
  #pragma unroll
  for(int cf=0;cf<16;++cf){
    int o = cf*16 + lo;
    float bia = bo[o];
    us4 xr = *(const us4*)(xn_cm + (size_t)(b*256+o)*1024 + p0r);
    float4 st;
    st.x = a2[cf][0] + bia + bf2f(xr[0]);
    st.y = a2[cf][1] + bia + bf2f(xr[1]);
    st.z = a2[cf][2] + bia + bf2f(xr[2]);
    st.w = a2[cf][3] + bia + bf2f(xr[3]);
    *(float4*)(out + (size_t)(b*256+o)*1024 + p0r) = st;
  }
}

extern "C" void kernel_launch(void* const* d_in, const int* in_sizes, int n_in,
                              void* d_out, int out_size, void* d_ws, size_t ws_size,
                              hipStream_t stream){
  (void)in_sizes; (void)n_in; (void)out_size; (void)ws_size;
  const float* x     = (const float*)d_in[0];
  const float* wq    = (const float*)d_in[1];
  const float* bq    = (const float*)d_in[2];
  const float* wk    = (const float*)d_in[3];
  const float* bk    = (const float*)d_in[4];
  const float* wv    = (const float*)d_in[5];
  const float* bv    = (const float*)d_in[6];
  const float* wo    = (const float*)d_in[7];
  const float* bo    = (const float*)d_in[8];
  const float* gamma = (const float*)d_in[9];
  const float* beta  = (const float*)d_in[10];
  float* out = (float*)d_out;
  char* ws = (char*)d_ws;
  unsigned short* xn_cm = (unsigned short*)(ws);
  unsigned short* xn_pm = (unsigned short*)(ws + 33554432);
  unsigned short* qb    = (unsigned short*)(ws + 67108864);
  unsigned short* kb    = (unsigned short*)(ws + 100663296);
  unsigned short* vT    = (unsigned short*)(ws + 134217728);
  unsigned short* wbf   = (unsigned short*)(ws + 167772160);

  hipLaunchKernelGGL(prep_kernel, dim3(256), dim3(256), 0, stream, wq, wk, wv, wo, wbf);
  hipLaunchKernelGGL(gn_kernel,   dim3(2048), dim3(256), 0, stream, x, gamma, beta, xn_cm, xn_pm);
  hipLaunchKernelGGL(qkv_kernel,  dim3(16,64,3), dim3(256), 0, stream,
                     xn_pm, wbf, bq, bk, bv, qb, kb, vT);
  hipLaunchKernelGGL(attn_kernel, dim3(512), dim3(512), 0, stream,
                     qb, kb, vT, wbf + 3*65536, bo, xn_cm, out);
}